// Round 1
// baseline (376.924 us; speedup 1.0000x reference)
//
#include <hip/hip_runtime.h>
#include <cstdint>
#include <cstddef>

typedef float f32x4 __attribute__((ext_vector_type(4)));

// ---------------------------------------------------------------------------
// helpers
// ---------------------------------------------------------------------------
__device__ __forceinline__ void async_copy16(const uint8_t* g, uint8_t* s) {
    __builtin_amdgcn_global_load_lds(
        (const __attribute__((address_space(1))) void*)g,
        (__attribute__((address_space(3))) void*)s,
        16 /*bytes*/, 0 /*offset*/, 0 /*aux*/);
}

// ---------------------------------------------------------------------------
// 1. zero the amax slots (ws is poisoned 0xAA before every timed call)
// ---------------------------------------------------------------------------
__global__ void init_slots(unsigned* slots) {
    slots[0] = 0u;
    slots[1] = 0u;
}

// ---------------------------------------------------------------------------
// 2. exact amax reduction (abs floats compare correctly as uint bits)
// ---------------------------------------------------------------------------
__global__ void amax_kernel(const float4* __restrict__ p, int n4,
                            unsigned* __restrict__ slot) {
    int i = blockIdx.x * blockDim.x + threadIdx.x;
    const int stride = gridDim.x * blockDim.x;
    float m = 0.0f;
    for (; i < n4; i += stride) {
        float4 v = p[i];
        m = fmaxf(m, fmaxf(fmaxf(fabsf(v.x), fabsf(v.y)),
                           fmaxf(fabsf(v.z), fabsf(v.w))));
    }
#pragma unroll
    for (int o = 32; o > 0; o >>= 1) m = fmaxf(m, __shfl_down(m, o, 64));
    __shared__ float wmax[8];
    const int lane = threadIdx.x & 63, wid = threadIdx.x >> 6;
    if (lane == 0) wmax[wid] = m;
    __syncthreads();
    if (threadIdx.x == 0) {
        float bm = wmax[0];
        const int nw = blockDim.x >> 6;
        for (int j = 1; j < nw; ++j) bm = fmaxf(bm, wmax[j]);
        atomicMax(slot, __float_as_uint(bm));
    }
}

// ---------------------------------------------------------------------------
// 3. quantize fp32 -> fp8 e4m3fn (OCP), 16 outputs / thread / iter
// ---------------------------------------------------------------------------
__global__ void quant_kernel(const float4* __restrict__ in, int n,
                             const unsigned* __restrict__ slot,
                             int4* __restrict__ out) {
    const float amax = __uint_as_float(*slot);
    const float scale = fmaxf(amax / 448.0f, 1e-12f);
    const float r = 1.0f / scale;
    const int n16 = n >> 4;
    const int stride = gridDim.x * blockDim.x;
    for (int i = blockIdx.x * blockDim.x + threadIdx.x; i < n16; i += stride) {
        int4 o;
#pragma unroll
        for (int j = 0; j < 4; ++j) {
            float4 v = in[i * 4 + j];
            int p = 0;
            p = __builtin_amdgcn_cvt_pk_fp8_f32(v.x * r, v.y * r, p, false);
            p = __builtin_amdgcn_cvt_pk_fp8_f32(v.z * r, v.w * r, p, true);
            ((int*)&o)[j] = p;
        }
        out[i] = o;
    }
}

// ---------------------------------------------------------------------------
// 4. fp8 GEMM: C[m,n] = (sum_k A[m,k]*B[n,k]) * scale + bias[n]
//    128x128 tile, BK=64, 256 thr (4 waves 2x2, each 64x64 via 4x4 MFMA tiles)
// ---------------------------------------------------------------------------
__global__ __launch_bounds__(256) void gemm_fp8_kernel(
    const uint8_t* __restrict__ A,   // [M][K] fp8
    const uint8_t* __restrict__ B,   // [N][K] fp8
    const float* __restrict__ bias,  // [N]
    const unsigned* __restrict__ slots,
    float* __restrict__ out,         // [M][N] fp32
    int M, int N, int K) {
    __shared__ long lds64[2048];     // 16 KiB: A tile [128][64B] + B tile
    uint8_t* Abase = (uint8_t*)lds64;
    uint8_t* Bbase = Abase + 8192;

    const int tid  = threadIdx.x;
    const int l    = tid & 63;
    const int w    = tid >> 6;
    const int lm   = l & 15;
    const int quad = l >> 4;
    const int wm   = (w >> 1) * 64;  // wave's M offset in tile
    const int wn   = (w & 1) * 64;   // wave's N offset in tile

    const size_t am0 = (size_t)blockIdx.y * 128;
    const size_t bn0 = (size_t)blockIdx.x * 128;

    const float ax = __uint_as_float(slots[0]);
    const float aw = __uint_as_float(slots[1]);
    const float scale = fmaxf(ax / 448.0f, 1e-12f) * fmaxf(aw / 448.0f, 1e-12f);

    f32x4 acc[4][4];
#pragma unroll
    for (int i = 0; i < 4; ++i)
#pragma unroll
        for (int j = 0; j < 4; ++j) acc[i][j] = (f32x4)0.0f;

    const int slot0 = w * 64 + l;  // 0..255; slot s -> row s/4, 16B-chunk s%4

    for (int kt = 0; kt < K; kt += 64) {
#pragma unroll
        for (int i = 0; i < 2; ++i) {
            const int s    = i * 256 + slot0;
            const int row  = s >> 2;
            const int chnk = s & 3;
            async_copy16(A + (am0 + row) * K + kt + chnk * 16,
                         Abase + (i * 4 + w) * 1024);
            async_copy16(B + (bn0 + row) * K + kt + chnk * 16,
                         Bbase + (i * 4 + w) * 1024);
        }
        __syncthreads();
#pragma unroll
        for (int ks = 0; ks < 2; ++ks) {
            long a[4], b[4];
#pragma unroll
            for (int t = 0; t < 4; ++t) {
                a[t] = lds64[(wm + t * 16 + lm) * 8 + ks * 4 + quad];
                b[t] = lds64[1024 + (wn + t * 16 + lm) * 8 + ks * 4 + quad];
            }
#pragma unroll
            for (int mt = 0; mt < 4; ++mt)
#pragma unroll
                for (int nt = 0; nt < 4; ++nt)
                    acc[mt][nt] = __builtin_amdgcn_mfma_f32_16x16x32_fp8_fp8(
                        a[mt], b[nt], acc[mt][nt], 0, 0, 0);
        }
        __syncthreads();
    }

    // epilogue: D row = quad*4+reg, col = lm (within each 16x16 tile)
#pragma unroll
    for (int nt = 0; nt < 4; ++nt) {
        const int n = (int)bn0 + wn + nt * 16 + lm;
        const float bv = bias[n];
#pragma unroll
        for (int mt = 0; mt < 4; ++mt) {
            const size_t mrow = am0 + wm + mt * 16 + quad * 4;
#pragma unroll
            for (int r = 0; r < 4; ++r) {
                out[(mrow + r) * (size_t)N + n] = acc[mt][nt][r] * scale + bv;
            }
        }
    }
}

// ---------------------------------------------------------------------------
// host launcher
// ---------------------------------------------------------------------------
extern "C" void kernel_launch(void* const* d_in, const int* in_sizes, int n_in,
                              void* d_out, int out_size, void* d_ws,
                              size_t ws_size, hipStream_t stream) {
    const float* x      = (const float*)d_in[0];
    const float* weight = (const float*)d_in[1];
    const float* bias   = (const float*)d_in[2];
    float* out          = (float*)d_out;

    const int nx = in_sizes[0];        // M*K = 33554432
    const int nw = in_sizes[1];        // N*K = 1048576
    const int N  = in_sizes[2];        // 1024
    const int K  = nw / N;             // 1024
    const int M  = nx / K;             // 32768

    unsigned* slots = (unsigned*)d_ws;
    uint8_t* x_fp8  = (uint8_t*)d_ws + 256;
    uint8_t* w_fp8  = x_fp8 + (size_t)nx;

    init_slots<<<1, 1, 0, stream>>>(slots);
    amax_kernel<<<1024, 256, 0, stream>>>((const float4*)x, nx / 4, slots + 0);
    amax_kernel<<<128, 256, 0, stream>>>((const float4*)weight, nw / 4, slots + 1);
    quant_kernel<<<2048, 256, 0, stream>>>((const float4*)x, nx, slots + 0,
                                           (int4*)x_fp8);
    quant_kernel<<<256, 256, 0, stream>>>((const float4*)weight, nw, slots + 1,
                                          (int4*)w_fp8);
    gemm_fp8_kernel<<<dim3(N / 128, M / 128), 256, 0, stream>>>(
        x_fp8, w_fp8, bias, slots, out, M, N, K);
}

// Round 2
// 318.391 us; speedup vs baseline: 1.1838x; 1.1838x over previous
//
#include <hip/hip_runtime.h>
#include <cstdint>
#include <cstddef>

typedef float f32x4 __attribute__((ext_vector_type(4)));
typedef long  lx2   __attribute__((ext_vector_type(2)));

#define PXB 1024   // partial-max blocks for x
#define PWB 64     // partial-max blocks for w
#define QXB 2048   // quant blocks for x
#define QWB 128    // quant blocks for w

// ---------------------------------------------------------------------------
// helpers
// ---------------------------------------------------------------------------
__device__ __forceinline__ void async_copy16(const uint8_t* g, uint8_t* s) {
    __builtin_amdgcn_global_load_lds(
        (const __attribute__((address_space(1))) void*)g,
        (__attribute__((address_space(3))) void*)s,
        16 /*bytes*/, 0 /*offset*/, 0 /*aux*/);
}

// block-wide max; every thread returns the result. Caller must not reuse
// scr until after a subsequent __syncthreads().
__device__ __forceinline__ float block_max(float m, float* scr) {
#pragma unroll
    for (int o = 32; o > 0; o >>= 1) m = fmaxf(m, __shfl_down(m, o, 64));
    const int lane = threadIdx.x & 63, wid = threadIdx.x >> 6;
    if (lane == 0) scr[wid] = m;
    __syncthreads();
    const int nw = blockDim.x >> 6;
    m = scr[0];
    for (int j = 1; j < nw; ++j) m = fmaxf(m, scr[j]);
    return m;
}

// ---------------------------------------------------------------------------
// 1. per-block amax partials (no atomics, no init kernel needed)
//    blocks [0,PXB) -> x, partials part[0..PXB); blocks [PXB,PXB+PWB) -> w
// ---------------------------------------------------------------------------
__global__ void amax_partials(const float4* __restrict__ x, int nx4,
                              const float4* __restrict__ w, int nw4,
                              float* __restrict__ part) {
    __shared__ float scr[8];
    const int b = blockIdx.x;
    const float4* p;
    int n4, nb, bi;
    if (b < PXB) { p = x; n4 = nx4; nb = PXB; bi = b; }
    else         { p = w; n4 = nw4; nb = PWB; bi = b - PXB; }
    float m = 0.0f;
    for (int i = bi * blockDim.x + threadIdx.x; i < n4; i += nb * blockDim.x) {
        float4 v = p[i];
        m = fmaxf(m, fmaxf(fmaxf(fabsf(v.x), fabsf(v.y)),
                           fmaxf(fabsf(v.z), fabsf(v.w))));
    }
    m = block_max(m, scr);
    if (threadIdx.x == 0) part[b] = m;
}

// ---------------------------------------------------------------------------
// 2. fused quantize fp32 -> fp8 e4m3fn for x and w in one grid
// ---------------------------------------------------------------------------
__global__ void quant_fused(const float4* __restrict__ x, int nx16,
                            const float4* __restrict__ w, int nw16,
                            const float* __restrict__ part,
                            int4* __restrict__ xq, int4* __restrict__ wq) {
    __shared__ float scr[8];
    const int b = blockIdx.x;
    const float4* in;
    const float* pp;
    int4* out;
    int n16, nb, bi, np;
    if (b < QXB) { in = x; n16 = nx16; nb = QXB; bi = b;       pp = part;       np = PXB; out = xq; }
    else         { in = w; n16 = nw16; nb = QWB; bi = b - QXB; pp = part + PXB; np = PWB; out = wq; }

    float m = 0.0f;
    for (int i = threadIdx.x; i < np; i += blockDim.x) m = fmaxf(m, pp[i]);
    m = block_max(m, scr);
    const float r = 1.0f / fmaxf(m / 448.0f, 1e-12f);

    for (int i = bi * blockDim.x + threadIdx.x; i < n16; i += nb * blockDim.x) {
        int4 o;
#pragma unroll
        for (int j = 0; j < 4; ++j) {
            float4 v = in[i * 4 + j];
            int p = 0;
            p = __builtin_amdgcn_cvt_pk_fp8_f32(v.x * r, v.y * r, p, false);
            p = __builtin_amdgcn_cvt_pk_fp8_f32(v.z * r, v.w * r, p, true);
            ((int*)&o)[j] = p;
        }
        out[i] = o;
    }
}

// ---------------------------------------------------------------------------
// 3. fp8 GEMM: C[m,n] = (sum_k A[m,k]*B[n,k]) * scale + bias[n]
//    128x128 tile, BK=64, 256 thr (4 waves 2x2, each 64x64 via 4x4 MFMA tiles)
//    Fragment K-permutation: frag(quad,ks) = row bytes [quad*16 + ks*8, +8).
//    Valid because A and B share the same K permutation; lets one
//    ds_read_b128 at row*64 + quad*16 fetch both ks fragments, and spreads
//    the wave across all 32 LDS banks uniformly.
// ---------------------------------------------------------------------------
__global__ __launch_bounds__(256) void gemm_fp8_kernel(
    const uint8_t* __restrict__ A,   // [M][K] fp8
    const uint8_t* __restrict__ B,   // [N][K] fp8
    const float* __restrict__ bias,  // [N]
    const float* __restrict__ part,  // amax partials
    float* __restrict__ out,         // [M][N] fp32
    int M, int N, int K) {
    __shared__ long lds64[2048];     // 16 KiB: A tile [128][64B] + B tile
    uint8_t* Abase = (uint8_t*)lds64;
    uint8_t* Bbase = Abase + 8192;

    const int tid  = threadIdx.x;
    const int l    = tid & 63;
    const int w    = tid >> 6;
    const int lm   = l & 15;
    const int quad = l >> 4;
    const int wm   = (w >> 1) * 64;  // wave's M offset in tile
    const int wn   = (w & 1) * 64;   // wave's N offset in tile

    const size_t am0 = (size_t)blockIdx.y * 128;
    const size_t bn0 = (size_t)blockIdx.x * 128;

    // per-tensor scales from partials (cheap block-local reduction)
    float* scr = (float*)lds64;
    float mx = 0.0f, mw = 0.0f;
    for (int i = tid; i < PXB; i += 256) mx = fmaxf(mx, part[i]);
    for (int i = tid; i < PWB; i += 256) mw = fmaxf(mw, part[PXB + i]);
    mx = block_max(mx, scr);
    mw = block_max(mw, scr + 8);
    const float scale = fmaxf(mx / 448.0f, 1e-12f) * fmaxf(mw / 448.0f, 1e-12f);
    __syncthreads();  // scr reads done before staging overwrites LDS

    f32x4 acc[4][4];
#pragma unroll
    for (int i = 0; i < 4; ++i)
#pragma unroll
        for (int j = 0; j < 4; ++j) acc[i][j] = (f32x4)0.0f;

    const int slot0 = w * 64 + l;  // 0..255; slot s -> row s/4, 16B-chunk s%4

    for (int kt = 0; kt < K; kt += 64) {
#pragma unroll
        for (int i = 0; i < 2; ++i) {
            const int s    = i * 256 + slot0;
            const int row  = s >> 2;
            const int chnk = s & 3;
            async_copy16(A + (am0 + row) * K + kt + chnk * 16,
                         Abase + (i * 4 + w) * 1024);
            async_copy16(B + (bn0 + row) * K + kt + chnk * 16,
                         Bbase + (i * 4 + w) * 1024);
        }
        __syncthreads();

        lx2 a[4], b[4];
#pragma unroll
        for (int t = 0; t < 4; ++t) {
            a[t] = *(const lx2*)&lds64[(wm + t * 16 + lm) * 8 + quad * 2];
            b[t] = *(const lx2*)&lds64[1024 + (wn + t * 16 + lm) * 8 + quad * 2];
        }
#pragma unroll
        for (int ks = 0; ks < 2; ++ks)
#pragma unroll
            for (int mt = 0; mt < 4; ++mt)
#pragma unroll
                for (int nt = 0; nt < 4; ++nt)
                    acc[mt][nt] = __builtin_amdgcn_mfma_f32_16x16x32_fp8_fp8(
                        a[mt][ks], b[nt][ks], acc[mt][nt], 0, 0, 0);
        __syncthreads();
    }

    // epilogue: D row = quad*4+reg, col = lm (within each 16x16 tile)
#pragma unroll
    for (int nt = 0; nt < 4; ++nt) {
        const int n = (int)bn0 + wn + nt * 16 + lm;
        const float bv = bias[n];
#pragma unroll
        for (int mt = 0; mt < 4; ++mt) {
            const size_t mrow = am0 + wm + mt * 16 + quad * 4;
#pragma unroll
            for (int r = 0; r < 4; ++r) {
                out[(mrow + r) * (size_t)N + n] = acc[mt][nt][r] * scale + bv;
            }
        }
    }
}

// ---------------------------------------------------------------------------
// host launcher
// ---------------------------------------------------------------------------
extern "C" void kernel_launch(void* const* d_in, const int* in_sizes, int n_in,
                              void* d_out, int out_size, void* d_ws,
                              size_t ws_size, hipStream_t stream) {
    const float* x      = (const float*)d_in[0];
    const float* weight = (const float*)d_in[1];
    const float* bias   = (const float*)d_in[2];
    float* out          = (float*)d_out;

    const int nx = in_sizes[0];        // M*K = 33554432
    const int nw = in_sizes[1];        // N*K = 1048576
    const int N  = in_sizes[2];        // 1024
    const int K  = nw / N;             // 1024
    const int M  = nx / K;             // 32768

    float* part     = (float*)d_ws;                 // PXB+PWB floats
    uint8_t* x_fp8  = (uint8_t*)d_ws + 8192;
    uint8_t* w_fp8  = x_fp8 + (size_t)nx;

    amax_partials<<<PXB + PWB, 256, 0, stream>>>(
        (const float4*)x, nx / 4, (const float4*)weight, nw / 4, part);
    quant_fused<<<QXB + QWB, 256, 0, stream>>>(
        (const float4*)x, nx / 16, (const float4*)weight, nw / 16, part,
        (int4*)x_fp8, (int4*)w_fp8);
    gemm_fp8_kernel<<<dim3(N / 128, M / 128), 256, 0, stream>>>(
        x_fp8, w_fp8, bias, part, out, M, N, K);
}